// Round 7
// baseline (323.171 us; speedup 1.0000x reference)
//
#include <hip/hip_runtime.h>

typedef unsigned short u16;
typedef short short8 __attribute__((ext_vector_type(8)));
typedef float floatx4 __attribute__((ext_vector_type(4)));

#define MFMA16(a, b, c) __builtin_amdgcn_mfma_f32_16x16x32_bf16((a), (b), (c), 0, 0, 0)

#define LD0 72    // u16 row stride (64-ch tiles)
#define LD2 136   // u16 row stride (128-ch tiles)

__device__ __forceinline__ float bits2f(unsigned u) {
  union { unsigned i; float f; } v; v.i = u; return v.f;
}
__device__ __forceinline__ u16 f2bf(float f) {
  union { float f; unsigned i; } v; v.f = f;
  return (u16)((v.i + 0x8000u) >> 16);
}
__device__ __forceinline__ short8 foldpack(const float* __restrict__ p, float s) {
  float4 u = *(const float4*)p, v = *(const float4*)(p + 4);
  short8 r;
  r[0] = (short)f2bf(s * u.x); r[1] = (short)f2bf(s * u.y);
  r[2] = (short)f2bf(s * u.z); r[3] = (short)f2bf(s * u.w);
  r[4] = (short)f2bf(s * v.x); r[5] = (short)f2bf(s * v.y);
  r[6] = (short)f2bf(s * v.z); r[7] = (short)f2bf(s * v.w);
  return r;
}

// ------------------------------------------------------------------
// Fully fused EdgeConv block: one kernel, 4096 blocks (b,n) x 256 thr.
// Per block: stage X[b] bf16 -> P-GEMM (MFMA, accs) + Q (VALU+shfl) ->
// H0 -> GEMM1 -> GEMM2 -> GEMM3+logits -> softmax -> fts -> out.
// Weights BN-folded per-lane into registers from raw fp32 (L1/L2-hot).
// LDS 39.7 KB -> 4 blocks/CU.
// ------------------------------------------------------------------
__global__ __launch_bounds__(256, 4) void k_fused(
    const float* __restrict__ feat, const float* __restrict__ w0,
    const float* __restrict__ g0, const float* __restrict__ b0, const float* __restrict__ m0, const float* __restrict__ v0,
    const float* __restrict__ w1, const float* __restrict__ g1, const float* __restrict__ b1, const float* __restrict__ m1, const float* __restrict__ v1,
    const float* __restrict__ w2, const float* __restrict__ g2, const float* __restrict__ b2, const float* __restrict__ m2, const float* __restrict__ v2,
    const float* __restrict__ wa0, const float* __restrict__ ga, const float* __restrict__ ba, const float* __restrict__ ma, const float* __restrict__ va,
    const float* __restrict__ wa1, const float* __restrict__ ba1,
    const float* __restrict__ wsc, const float* __restrict__ gsc, const float* __restrict__ bsc, const float* __restrict__ msc, const float* __restrict__ vsc,
    float* __restrict__ out)
{
  __shared__ alignas(16) u16 buf[18432];   // A=[0,9216) u16, B=[9216,18432); H2 overlays A∪B (stride 136)
  __shared__ float parts[4][128];
  __shared__ float attws[128];
  __shared__ alignas(16) float xns[64];

  const int blk = blockIdx.x, b = blk >> 7, n = blk & 127, t = threadIdx.x;
  const int lane = t & 63, wid = t >> 6, quad = lane >> 4, l16 = lane & 15;
  const int koff = quad * 8;
  const float* featb = feat + b * 8192;

  u16* Xw = buf + 9216;     // Xbf[j][c], stride LD0 (region B, phase 0-1)
  u16* H0 = buf;            // region A
  u16* H1 = buf + 9216;     // region B (after barrier 2)
  u16* H2 = buf;            // overlay, stride LD2 (after barrier 4)

  // ---------- per-lane BN-folded weight fragments (registers) ----------
  const int ch = wid * 16 + l16;             // A-row for P/G1/G3
  const float s1r = g1[ch] * rsqrtf(v1[ch] + 1e-5f);
  const short8 a1w0 = foldpack(w1 + ch * 64 + koff, s1r);
  const short8 a1w1 = foldpack(w1 + ch * 64 + 32 + koff, s1r);
  const int ch2a = wid * 32 + l16, ch2b = ch2a + 16;
  const float s2a = g2[ch2a] * rsqrtf(v2[ch2a] + 1e-5f);
  const float s2b = g2[ch2b] * rsqrtf(v2[ch2b] + 1e-5f);
  const short8 a2w00 = foldpack(w2 + ch2a * 64 + koff, s2a);
  const short8 a2w01 = foldpack(w2 + ch2a * 64 + 32 + koff, s2a);
  const short8 a2w10 = foldpack(w2 + ch2b * 64 + koff, s2b);
  const short8 a2w11 = foldpack(w2 + ch2b * 64 + 32 + koff, s2b);
  // P-GEMM A = s0*B0 (right half of w0 rows)
  const float s0r = g0[ch] * rsqrtf(v0[ch] + 1e-5f);
  const short8 a0f0 = foldpack(w0 + ch * 128 + 64 + koff, s0r);
  const short8 a0f1 = foldpack(w0 + ch * 128 + 64 + 32 + koff, s0r);

  // biases (per-lane float4 at row r0)
  const int r0 = wid * 16 + quad * 4;
  float4 bb1, bb2a, bb2b, bbA, wv;
  {
    float4 gv = *(const float4*)(g1 + r0), bv = *(const float4*)(b1 + r0);
    float4 mv = *(const float4*)(m1 + r0), vv = *(const float4*)(v1 + r0);
    bb1.x = bv.x - mv.x * gv.x * rsqrtf(vv.x + 1e-5f);
    bb1.y = bv.y - mv.y * gv.y * rsqrtf(vv.y + 1e-5f);
    bb1.z = bv.z - mv.z * gv.z * rsqrtf(vv.z + 1e-5f);
    bb1.w = bv.w - mv.w * gv.w * rsqrtf(vv.w + 1e-5f);
  }
  {
    const int r2 = wid * 32 + quad * 4;
    float4 gv = *(const float4*)(g2 + r2), bv = *(const float4*)(b2 + r2);
    float4 mv = *(const float4*)(m2 + r2), vv = *(const float4*)(v2 + r2);
    bb2a.x = bv.x - mv.x * gv.x * rsqrtf(vv.x + 1e-5f);
    bb2a.y = bv.y - mv.y * gv.y * rsqrtf(vv.y + 1e-5f);
    bb2a.z = bv.z - mv.z * gv.z * rsqrtf(vv.z + 1e-5f);
    bb2a.w = bv.w - mv.w * gv.w * rsqrtf(vv.w + 1e-5f);
    gv = *(const float4*)(g2 + r2 + 16); bv = *(const float4*)(b2 + r2 + 16);
    mv = *(const float4*)(m2 + r2 + 16); vv = *(const float4*)(v2 + r2 + 16);
    bb2b.x = bv.x - mv.x * gv.x * rsqrtf(vv.x + 1e-5f);
    bb2b.y = bv.y - mv.y * gv.y * rsqrtf(vv.y + 1e-5f);
    bb2b.z = bv.z - mv.z * gv.z * rsqrtf(vv.z + 1e-5f);
    bb2b.w = bv.w - mv.w * gv.w * rsqrtf(vv.w + 1e-5f);
  }
  {
    float4 gv = *(const float4*)(ga + r0), bv = *(const float4*)(ba + r0);
    float4 mv = *(const float4*)(ma + r0), vv = *(const float4*)(va + r0);
    bbA.x = bv.x - mv.x * gv.x * rsqrtf(vv.x + 1e-5f);
    bbA.y = bv.y - mv.y * gv.y * rsqrtf(vv.y + 1e-5f);
    bbA.z = bv.z - mv.z * gv.z * rsqrtf(vv.z + 1e-5f);
    bbA.w = bv.w - mv.w * gv.w * rsqrtf(vv.w + 1e-5f);
    wv = *(const float4*)(wa1 + r0);
  }
  const float ba1v = ba1[0];

  // ---------- phase 0: stage Xbf[j][c] (bf16, stride LD0) + xns ----------
  {
    const int c0 = (t & 15) * 4, j0 = (t >> 4) * 8;
    #pragma unroll
    for (int jj = 0; jj < 8; jj += 4) {
      float4 f0 = *(const float4*)(featb + (c0 + 0) * 128 + j0 + jj);
      float4 f1 = *(const float4*)(featb + (c0 + 1) * 128 + j0 + jj);
      float4 f2 = *(const float4*)(featb + (c0 + 2) * 128 + j0 + jj);
      float4 f3 = *(const float4*)(featb + (c0 + 3) * 128 + j0 + jj);
      ushort4 s0v = { f2bf(f0.x), f2bf(f1.x), f2bf(f2.x), f2bf(f3.x) };
      ushort4 s1v = { f2bf(f0.y), f2bf(f1.y), f2bf(f2.y), f2bf(f3.y) };
      ushort4 s2v = { f2bf(f0.z), f2bf(f1.z), f2bf(f2.z), f2bf(f3.z) };
      ushort4 s3v = { f2bf(f0.w), f2bf(f1.w), f2bf(f2.w), f2bf(f3.w) };
      *(ushort4*)(Xw + (j0 + jj + 0) * LD0 + c0) = s0v;
      *(ushort4*)(Xw + (j0 + jj + 1) * LD0 + c0) = s1v;
      *(ushort4*)(Xw + (j0 + jj + 2) * LD0 + c0) = s2v;
      *(ushort4*)(Xw + (j0 + jj + 3) * LD0 + c0) = s3v;
    }
    if (t < 64) xns[t] = featb[t * 128 + n];
  }
  __syncthreads();                                           // (1)

  // ---------- phase 1: P-GEMM (MFMA) + Q (VALU) -> H0; SC ----------
  {
    floatx4 pacc[8];
    #pragma unroll
    for (int jt = 0; jt < 8; jt++) pacc[jt] = (floatx4)(0.f);
    #pragma unroll
    for (int jt = 0; jt < 8; jt++) {
      const u16* br = Xw + (jt * 16 + l16) * LD0 + koff;
      short8 bf0 = *(const short8*)(br);
      short8 bf1 = *(const short8*)(br + 32);
      pacc[jt] = MFMA16(a0f0, bf0, pacc[jt]);
      pacc[jt] = MFMA16(a0f1, bf1, pacc[jt]);
    }
    // Q[ch] = s0*( (A0-B0) @ x_n ) + t0  — all lanes, ch = wid*16+l16
    float qa = 0.f;
    const float4* wr = (const float4*)(w0 + ch * 128);
    #pragma unroll
    for (int k4 = 0; k4 < 16; k4++) {
      float4 wa = wr[k4], wbv = wr[16 + k4];
      float4 x = *(const float4*)(xns + k4 * 4);
      qa += (wa.x - wbv.x) * x.x + (wa.y - wbv.y) * x.y
          + (wa.z - wbv.z) * x.z + (wa.w - wbv.w) * x.w;
    }
    const float qv = s0r * qa + (b0[ch] - m0[ch] * s0r);
    // lane needs Q at rows r0..r0+3 -> from lanes quad*16 + quad*4 + r
    float4 qf;
    qf.x = __shfl(qv, quad * 20 + 0);
    qf.y = __shfl(qv, quad * 20 + 1);
    qf.z = __shfl(qv, quad * 20 + 2);
    qf.w = __shfl(qv, quad * 20 + 3);
    // H0[edge k][ch] = relu(Q + P[j]);  k = j<n ? j : (j>n ? j-1 : 127)
    const int ch0 = wid * 16 + quad * 4;
    #pragma unroll
    for (int jt = 0; jt < 8; jt++) {
      const int j = jt * 16 + l16;
      const int k = (j < n) ? j : ((j > n) ? (j - 1) : 127);
      ushort4 sv;
      sv.x = f2bf(fmaxf(qf.x + pacc[jt][0], 0.f));
      sv.y = f2bf(fmaxf(qf.y + pacc[jt][1], 0.f));
      sv.z = f2bf(fmaxf(qf.z + pacc[jt][2], 0.f));
      sv.w = f2bf(fmaxf(qf.w + pacc[jt][3], 0.f));
      *(ushort4*)(H0 + k * LD0 + ch0) = sv;
    }
  }
  // SC[ch] for own n (t<128), overlapped with barrier wait
  float scv = 0.f;
  if (t < 128) {
    const float ssc = gsc[t] * rsqrtf(vsc[t] + 1e-5f);
    const float tsc = bsc[t] - msc[t] * ssc;
    const float4* wr = (const float4*)(wsc + t * 64);
    float d = 0.f;
    #pragma unroll
    for (int k4 = 0; k4 < 16; k4++) {
      float4 a = wr[k4];
      float4 x = *(const float4*)(xns + k4 * 4);
      d += a.x * x.x + a.y * x.y + a.z * x.z + a.w * x.w;
    }
    scv = ssc * d + tsc;
  }
  float* outp = out + ((b << 7) + (t & 127)) * 128 + n;
  __syncthreads();                                           // (2)

  // ---------- GEMM1: H1 rows wid*16..+15 ----------
  {
    floatx4 acc[8];
    #pragma unroll
    for (int et = 0; et < 8; et++) acc[et] = (floatx4)(0.f);
    #pragma unroll
    for (int et = 0; et < 8; et++) {
      const u16* br = H0 + (et * 16 + l16) * LD0 + koff;
      short8 bf0 = *(const short8*)(br);
      short8 bf1 = *(const short8*)(br + 32);
      acc[et] = MFMA16(a1w0, bf0, acc[et]);
      acc[et] = MFMA16(a1w1, bf1, acc[et]);
    }
    const int rr = wid * 16 + quad * 4;
    #pragma unroll
    for (int et = 0; et < 8; et++) {
      ushort4 sv;
      sv.x = f2bf(fmaxf(acc[et][0] + bb1.x, 0.f));
      sv.y = f2bf(fmaxf(acc[et][1] + bb1.y, 0.f));
      sv.z = f2bf(fmaxf(acc[et][2] + bb1.z, 0.f));
      sv.w = f2bf(fmaxf(acc[et][3] + bb1.w, 0.f));
      *(ushort4*)(H1 + (et * 16 + l16) * LD0 + rr) = sv;
    }
  }
  __syncthreads();                                           // (3)

  // ---------- GEMM2: H2 rows wid*32..+31 (register-staged) ----------
  {
    floatx4 acc[2][8];
    #pragma unroll
    for (int m = 0; m < 2; m++)
      #pragma unroll
      for (int et = 0; et < 8; et++) acc[m][et] = (floatx4)(0.f);
    #pragma unroll
    for (int et = 0; et < 8; et++) {
      const u16* br = H1 + (et * 16 + l16) * LD0 + koff;
      short8 bf0 = *(const short8*)(br);
      short8 bf1 = *(const short8*)(br + 32);
      acc[0][et] = MFMA16(a2w00, bf0, acc[0][et]);
      acc[0][et] = MFMA16(a2w01, bf1, acc[0][et]);
      acc[1][et] = MFMA16(a2w10, bf0, acc[1][et]);
      acc[1][et] = MFMA16(a2w11, bf1, acc[1][et]);
    }
    __syncthreads();                                         // (4) H1 reads done
    #pragma unroll
    for (int m = 0; m < 2; m++) {
      const int rr = wid * 32 + m * 16 + quad * 4;
      const float4 bb = m ? bb2b : bb2a;
      #pragma unroll
      for (int et = 0; et < 8; et++) {
        ushort4 sv;
        sv.x = f2bf(fmaxf(acc[m][et][0] + bb.x, 0.f));
        sv.y = f2bf(fmaxf(acc[m][et][1] + bb.y, 0.f));
        sv.z = f2bf(fmaxf(acc[m][et][2] + bb.z, 0.f));
        sv.w = f2bf(fmaxf(acc[m][et][3] + bb.w, 0.f));
        *(ushort4*)(H2 + (et * 16 + l16) * LD2 + rr) = sv;
      }
    }
  }
  __syncthreads();                                           // (5)

  // ---------- GEMM3 + logits ----------
  {
    const float sar = ga[ch] * rsqrtf(va[ch] + 1e-5f);
    short8 a3[4];
    #pragma unroll
    for (int ks = 0; ks < 4; ks++)
      a3[ks] = foldpack(wa0 + ch * 128 + ks * 32 + koff, sar);
    floatx4 acc[8];
    #pragma unroll
    for (int et = 0; et < 8; et++) acc[et] = (floatx4)(0.f);
    #pragma unroll
    for (int et = 0; et < 8; et++) {
      const u16* br = H2 + (et * 16 + l16) * LD2 + koff;
      #pragma unroll
      for (int ks = 0; ks < 4; ks++) {
        short8 bf = *(const short8*)(br + ks * 32);
        acc[et] = MFMA16(a3[ks], bf, acc[et]);
      }
    }
    #pragma unroll
    for (int et = 0; et < 8; et++) {
      float p = wv.x * fmaxf(acc[et][0] + bbA.x, 0.f) + wv.y * fmaxf(acc[et][1] + bbA.y, 0.f)
              + wv.z * fmaxf(acc[et][2] + bbA.z, 0.f) + wv.w * fmaxf(acc[et][3] + bbA.w, 0.f);
      p += __shfl_xor(p, 16); p += __shfl_xor(p, 32);
      if (quad == 0) parts[wid][et * 16 + l16] = p;
    }
  }
  __syncthreads();                                           // (6)

  // ---------- softmax over 127 edges (wave 0) ----------
  if (wid == 0) {
    float a0 = parts[0][lane] + parts[1][lane] + parts[2][lane] + parts[3][lane] + ba1v;
    float a1 = (lane == 63) ? -1e30f
             : (parts[0][lane + 64] + parts[1][lane + 64] + parts[2][lane + 64] + parts[3][lane + 64] + ba1v);
    float mx = fmaxf(a0, a1);
    #pragma unroll
    for (int off = 32; off >= 1; off >>= 1) mx = fmaxf(mx, __shfl_xor(mx, off));
    float e0 = expf(a0 - mx), e1 = expf(a1 - mx);
    float sm = e0 + e1;
    #pragma unroll
    for (int off = 32; off >= 1; off >>= 1) sm += __shfl_xor(sm, off);
    float inv = 1.f / sm;
    attws[lane] = e0 * inv;
    attws[lane + 64] = e1 * inv;   // attw[127] = 0
  }
  __syncthreads();                                           // (7)

  // ---------- fts[c] = sum_e attw[e]*H2[e][c] ----------
  {
    const int chg = t & 15, eg = t >> 4;
    float fa[8];
    #pragma unroll
    for (int k = 0; k < 8; k++) fa[k] = 0.f;
    #pragma unroll
    for (int i = 0; i < 8; i++) {
      const int e = eg * 8 + i;
      const float w = attws[e];
      uint4 v = *(const uint4*)(H2 + e * LD2 + chg * 8);
      unsigned u;
      u = v.x; fa[0] += w * bits2f(u << 16); fa[1] += w * bits2f(u & 0xffff0000u);
      u = v.y; fa[2] += w * bits2f(u << 16); fa[3] += w * bits2f(u & 0xffff0000u);
      u = v.z; fa[4] += w * bits2f(u << 16); fa[5] += w * bits2f(u & 0xffff0000u);
      u = v.w; fa[6] += w * bits2f(u << 16); fa[7] += w * bits2f(u & 0xffff0000u);
    }
    #pragma unroll
    for (int k = 0; k < 8; k++) { fa[k] += __shfl_xor(fa[k], 16); fa[k] += __shfl_xor(fa[k], 32); }
    if (lane < 16) {
      #pragma unroll
      for (int k = 0; k < 8; k++) parts[wid][chg * 8 + k] = fa[k];
    }
  }
  __syncthreads();                                           // (8)

  if (t < 128) {
    float fts = parts[0][t] + parts[1][t] + parts[2][t] + parts[3][t];
    *outp = fmaxf(scv + fts, 0.f);
  }
}

// ------------------------------------------------------------------
extern "C" void kernel_launch(void* const* d_in, const int* in_sizes, int n_in,
                              void* d_out, int out_size, void* d_ws, size_t ws_size,
                              hipStream_t stream)
{
  (void)d_ws; (void)ws_size; (void)in_sizes; (void)n_in; (void)out_size;
  const float* feat = (const float*)d_in[0];
  const float *w0 = (const float*)d_in[1],  *g0 = (const float*)d_in[2],  *b0 = (const float*)d_in[3],  *m0 = (const float*)d_in[4],  *v0 = (const float*)d_in[5];
  const float *w1 = (const float*)d_in[6],  *g1 = (const float*)d_in[7],  *b1 = (const float*)d_in[8],  *m1 = (const float*)d_in[9],  *v1 = (const float*)d_in[10];
  const float *w2 = (const float*)d_in[11], *g2 = (const float*)d_in[12], *b2 = (const float*)d_in[13], *m2 = (const float*)d_in[14], *v2 = (const float*)d_in[15];
  const float *wa0= (const float*)d_in[16], *ga = (const float*)d_in[17], *ba = (const float*)d_in[18], *ma = (const float*)d_in[19], *va = (const float*)d_in[20];
  const float *wa1= (const float*)d_in[21], *ba1= (const float*)d_in[22];
  const float *wsc= (const float*)d_in[23], *gsc= (const float*)d_in[24], *bsc= (const float*)d_in[25], *msc= (const float*)d_in[26], *vsc= (const float*)d_in[27];

  k_fused<<<dim3(4096), dim3(256), 0, stream>>>(
      feat, w0, g0, b0, m0, v0, w1, g1, b1, m1, v1, w2, g2, b2, m2, v2,
      wa0, ga, ba, ma, va, wa1, ba1, wsc, gsc, bsc, msc, vsc, (float*)d_out);
}

// Round 8
// 166.560 us; speedup vs baseline: 1.9403x; 1.9403x over previous
//
#include <hip/hip_runtime.h>

typedef unsigned short u16;
typedef short short8 __attribute__((ext_vector_type(8)));
typedef float floatx4 __attribute__((ext_vector_type(4)));

#define MFMA16(a, b, c) __builtin_amdgcn_mfma_f32_16x16x32_bf16((a), (b), (c), 0, 0, 0)

// ---- g_ws byte offsets (256-aligned) ----
#define W1F_OFF   0u         // bf16[4096]
#define B1F_OFF   8192u      // f32[64]
#define W2F_OFF   8448u      // bf16[8192]
#define B2F_OFF   24832u     // f32[128]
#define WA0F_OFF  25344u     // bf16[8192]
#define BAF_OFF   41728u     // f32[64]
#define WA1F_OFF  41984u     // f32[64]
#define BA1F_OFF  42240u     // f32[1]
#define P_OFF     42496u     // f32[32*128*64]
#define Q_OFF     1091072u   // f32[32*128*64]
#define SC_OFF    2139648u   // f32[32*128*128]
#define WS_TOTAL  4236800u

__device__ __align__(256) char g_ws[WS_TOTAL];

#define LD0 72    // u16 row stride (64-ch) — 16B-aligned rows
#define LD2 136   // u16 row stride (128-ch) — 16B-aligned rows

__device__ __forceinline__ float bits2f(unsigned u) {
  union { unsigned i; float f; } v; v.i = u; return v.f;
}
__device__ __forceinline__ unsigned f2bits(float f) {
  union { float f; unsigned i; } v; v.f = f; return v.i;
}
__device__ __forceinline__ u16 f2bf(float f) {
  return (u16)((f2bits(f) + 0x8000u) >> 16);
}
// two fp32 -> relu -> bf16 pair packed in one dword (lo=a, hi=b); ~6 VALU
__device__ __forceinline__ unsigned pack2relu(float a, float b) {
  unsigned lo = (f2bits(fmaxf(a, 0.f)) + 0x8000u) >> 16;
  unsigned hi = (f2bits(fmaxf(b, 0.f)) + 0x8000u) & 0xffff0000u;
  return lo | hi;   // v_and_or_b32
}

// ------------------------------------------------------------------
// k_pre: 513 blocks x 256.  (unchanged from R6 — measured fine)
//   blocks   0..255: P/Q for (b = sub>>3, n0 = (sub&7)*16)
//   blocks 256..511: SC  for same (b, n0)
//   block  512:      fold W1/W2/Wa0 (bf16) + biases
// ------------------------------------------------------------------
__global__ __launch_bounds__(256) void k_pre(
    const float* __restrict__ feat, const float* __restrict__ w0,
    const float* __restrict__ g0, const float* __restrict__ b0, const float* __restrict__ m0, const float* __restrict__ v0,
    const float* __restrict__ w1, const float* __restrict__ g1, const float* __restrict__ b1, const float* __restrict__ m1, const float* __restrict__ v1,
    const float* __restrict__ w2, const float* __restrict__ g2, const float* __restrict__ b2, const float* __restrict__ m2, const float* __restrict__ v2,
    const float* __restrict__ wa0, const float* __restrict__ ga, const float* __restrict__ ba, const float* __restrict__ ma, const float* __restrict__ va,
    const float* __restrict__ wa1, const float* __restrict__ ba1,
    const float* __restrict__ wsc, const float* __restrict__ gsc, const float* __restrict__ bsc, const float* __restrict__ msc, const float* __restrict__ vsc)
{
  __shared__ float smem[9600];
  const int t = threadIdx.x;
  char* ws = g_ws;
  const int blk = blockIdx.x;

  if (blk == 512) {
    float* fs1 = smem; float* fs2 = smem + 64; float* fsa = smem + 192;
    if (t < 64) {
      float s;
      s = g1[t] * rsqrtf(v1[t] + 1e-5f); fs1[t] = s; ((float*)(ws + B1F_OFF))[t] = b1[t] - m1[t] * s;
      s = ga[t] * rsqrtf(va[t] + 1e-5f); fsa[t] = s; ((float*)(ws + BAF_OFF))[t] = ba[t] - ma[t] * s;
      ((float*)(ws + WA1F_OFF))[t] = wa1[t];
    }
    if (t < 128) { float s = g2[t] * rsqrtf(v2[t] + 1e-5f); fs2[t] = s; ((float*)(ws + B2F_OFF))[t] = b2[t] - m2[t] * s; }
    if (t == 0) ((float*)(ws + BA1F_OFF))[0] = ba1[0];
    __syncthreads();
    u16* W1f = (u16*)(ws + W1F_OFF);
    u16* W2f = (u16*)(ws + W2F_OFF);
    u16* Wa0f = (u16*)(ws + WA0F_OFF);
    for (int i = t; i < 4096; i += 256) W1f[i]  = f2bf(fs1[i >> 6] * w1[i]);
    for (int i = t; i < 8192; i += 256) W2f[i]  = f2bf(fs2[i >> 6] * w2[i]);
    for (int i = t; i < 8192; i += 256) Wa0f[i] = f2bf(fsa[i >> 7] * wa0[i]);
    return;
  }

  const int sub = blk & 255;
  const int b = sub >> 3, n0 = (sub & 7) << 4;
  float* Xs  = smem;          // [64][20]
  float* Wsm = smem + 1280;

  {
    const int c = t >> 2, j = (t & 3) << 2;
    *(float4*)(Xs + c * 20 + j) = *(const float4*)(feat + b * 8192 + c * 128 + n0 + j);
  }

  if (blk < 256) {
    #pragma unroll
    for (int r = 0; r < 8; r++) {
      const int i = (r * 256 + t) * 4;
      float4 v = *(const float4*)(w0 + i);
      const int o = i >> 7, c = i & 127;
      float* d = Wsm + o * 129 + c;
      d[0] = v.x; d[1] = v.y; d[2] = v.z; d[3] = v.w;
    }
    __syncthreads();
    const int o = t & 63, nb = (t >> 6) << 2;
    const float s  = g0[o] * rsqrtf(v0[o] + 1e-5f);
    const float tt = b0[o] - m0[o] * s;
    const float* wr = Wsm + o * 129;
    float dA0=0.f,dA1=0.f,dA2=0.f,dA3=0.f,dB0=0.f,dB1=0.f,dB2=0.f,dB3=0.f;
    #pragma unroll
    for (int c = 0; c < 64; c++) {
      const float a = wr[c], e = wr[64 + c];
      const float4 x = *(const float4*)(Xs + c * 20 + nb);
      dA0 += a * x.x; dA1 += a * x.y; dA2 += a * x.z; dA3 += a * x.w;
      dB0 += e * x.x; dB1 += e * x.y; dB2 += e * x.z; dB3 += e * x.w;
    }
    float* Pp = (float*)(ws + P_OFF) + (b * 128 + n0 + nb) * 64 + o;
    float* Qp = (float*)(ws + Q_OFF) + (b * 128 + n0 + nb) * 64 + o;
    Pp[0]   = s * dB0; Pp[64]  = s * dB1; Pp[128] = s * dB2; Pp[192] = s * dB3;
    Qp[0]   = s * (dA0 - dB0) + tt; Qp[64]  = s * (dA1 - dB1) + tt;
    Qp[128] = s * (dA2 - dB2) + tt; Qp[192] = s * (dA3 - dB3) + tt;
  } else {
    #pragma unroll
    for (int r = 0; r < 8; r++) {
      const int i = (r * 256 + t) * 4;
      float4 v = *(const float4*)(wsc + i);
      const int o = i >> 6, c = i & 63;
      float* d = Wsm + o * 65 + c;
      d[0] = v.x; d[1] = v.y; d[2] = v.z; d[3] = v.w;
    }
    __syncthreads();
    const int o = t & 127, h = (t >> 7) << 3;
    const float s  = gsc[o] * rsqrtf(vsc[o] + 1e-5f);
    const float tt = bsc[o] - msc[o] * s;
    const float* wr = Wsm + o * 65;
    float d0=0.f,d1=0.f,d2=0.f,d3=0.f,d4=0.f,d5=0.f,d6=0.f,d7=0.f;
    #pragma unroll
    for (int c = 0; c < 64; c++) {
      const float a = wr[c];
      const float4 x0 = *(const float4*)(Xs + c * 20 + h);
      const float4 x1 = *(const float4*)(Xs + c * 20 + h + 4);
      d0 += a * x0.x; d1 += a * x0.y; d2 += a * x0.z; d3 += a * x0.w;
      d4 += a * x1.x; d5 += a * x1.y; d6 += a * x1.z; d7 += a * x1.w;
    }
    float* SCp = (float*)(ws + SC_OFF) + (b * 128 + n0 + h) * 128 + o;
    SCp[0]   = s * d0 + tt; SCp[128] = s * d1 + tt; SCp[256] = s * d2 + tt; SCp[384] = s * d3 + tt;
    SCp[512] = s * d4 + tt; SCp[640] = s * d5 + tt; SCp[768] = s * d6 + tt; SCp[896] = s * d7 + tt;
  }
}

// ------------------------------------------------------------------
// k_main: fused edge chain per (b,n). 4096 blocks x 256 thr (4 waves).
// R8: bias folded into MFMA acc-init; pack2relu epilogues (~3 VALU/el
// vs ~5-6). Structure identical to R6 (no spills: VGPR ~60).
// ------------------------------------------------------------------
__global__ __launch_bounds__(256, 4) void k_main(float* __restrict__ out)
{
  __shared__ alignas(16) u16 buf[18432];     // H0@0, H1@9216(u16); H2 overlays @0 (stride 136)
  __shared__ float parts[4][128];
  __shared__ float attws[128];

  const int blk = blockIdx.x, b = blk >> 7, n = blk & 127, t = threadIdx.x;
  const char* ws = g_ws;
  const float* Pb  = (const float*)(ws + P_OFF);
  const float* Qb  = (const float*)(ws + Q_OFF);
  const float* SCb = (const float*)(ws + SC_OFF);
  const u16*   W1f = (const u16*)(ws + W1F_OFF);
  const float* b1f = (const float*)(ws + B1F_OFF);
  const u16*   W2f = (const u16*)(ws + W2F_OFF);
  const float* b2f = (const float*)(ws + B2F_OFF);
  const u16*   Wa0f= (const u16*)(ws + WA0F_OFF);
  const float* baf = (const float*)(ws + BAF_OFF);
  const float* wa1f= (const float*)(ws + WA1F_OFF);
  const float  ba1v= *(const float*)(ws + BA1F_OFF);

  u16* H0 = buf;
  u16* H1 = buf + 9216;
  u16* H2 = buf;            // after barrier (3)

  const int lane = t & 63, wid = t >> 6, quad = lane >> 4, l16 = lane & 15;
  const int koff = quad * 8;

  // hoisted A-fragments (no LDS dependence)
  const short8 a1w0 = *(const short8*)(W1f + (wid * 16 + l16) * 64 + koff);
  const short8 a1w1 = *(const short8*)(W1f + (wid * 16 + l16) * 64 + 32 + koff);
  const short8 a2w00 = *(const short8*)(W2f + (wid * 32 + l16) * 64 + koff);
  const short8 a2w01 = *(const short8*)(W2f + (wid * 32 + l16) * 64 + 32 + koff);
  const short8 a2w10 = *(const short8*)(W2f + (wid * 32 + 16 + l16) * 64 + koff);
  const short8 a2w11 = *(const short8*)(W2f + (wid * 32 + 16 + l16) * 64 + 32 + koff);

  // ---- L0: H0[edge][ch] = relu(Q[b,n] + P[b,j]); edge 127 dummy ----
  {
    const int k = t >> 1, half = t & 1;
    const int j = (k < 127) ? ((k < n) ? k : (k + 1)) : n;
    const float4* pr = (const float4*)(Pb + ((b << 7) + j) * 64 + half * 32);
    const float4* qr = (const float4*)(Qb + blk * 64 + half * 32);
    u16* dst = H0 + k * LD0 + half * 32;
    #pragma unroll
    for (int i = 0; i < 8; i++) {
      float4 p = pr[i], q = qr[i];
      uint2 sv;
      sv.x = pack2relu(q.x + p.x, q.y + p.y);
      sv.y = pack2relu(q.z + p.z, q.w + p.w);
      *(uint2*)(dst + i * 4) = sv;
    }
  }
  __syncthreads();                                           // (1)

  // ---- GEMM1: wave owns rows wid*16..+15 of H1; acc init = bias ----
  {
    const int rr = wid * 16 + quad * 4;
    const float4 bb = *(const float4*)(b1f + rr);
    floatx4 binit; binit[0] = bb.x; binit[1] = bb.y; binit[2] = bb.z; binit[3] = bb.w;
    floatx4 acc[8];
    #pragma unroll
    for (int et = 0; et < 8; et++) acc[et] = binit;
    #pragma unroll
    for (int et = 0; et < 8; et++) {
      const u16* br = H0 + (et * 16 + l16) * LD0 + koff;
      short8 bf0 = *(const short8*)(br);
      short8 bf1 = *(const short8*)(br + 32);
      acc[et] = MFMA16(a1w0, bf0, acc[et]);
      acc[et] = MFMA16(a1w1, bf1, acc[et]);
    }
    #pragma unroll
    for (int et = 0; et < 8; et++) {
      uint2 sv;
      sv.x = pack2relu(acc[et][0], acc[et][1]);
      sv.y = pack2relu(acc[et][2], acc[et][3]);
      *(uint2*)(H1 + (et * 16 + l16) * LD0 + rr) = sv;
    }
  }
  __syncthreads();                                           // (2)

  // ---- GEMM2: wave owns rows wid*32..+31 of H2; register-staged ----
  {
    const int r2 = wid * 32 + quad * 4;
    const float4 bba = *(const float4*)(b2f + r2);
    const float4 bbb = *(const float4*)(b2f + r2 + 16);
    floatx4 ia; ia[0] = bba.x; ia[1] = bba.y; ia[2] = bba.z; ia[3] = bba.w;
    floatx4 ib; ib[0] = bbb.x; ib[1] = bbb.y; ib[2] = bbb.z; ib[3] = bbb.w;
    floatx4 acc[2][8];
    #pragma unroll
    for (int et = 0; et < 8; et++) { acc[0][et] = ia; acc[1][et] = ib; }
    #pragma unroll
    for (int et = 0; et < 8; et++) {
      const u16* br = H1 + (et * 16 + l16) * LD0 + koff;
      short8 bf0 = *(const short8*)(br);
      short8 bf1 = *(const short8*)(br + 32);
      acc[0][et] = MFMA16(a2w00, bf0, acc[0][et]);
      acc[0][et] = MFMA16(a2w01, bf1, acc[0][et]);
      acc[1][et] = MFMA16(a2w10, bf0, acc[1][et]);
      acc[1][et] = MFMA16(a2w11, bf1, acc[1][et]);
    }
    __syncthreads();                                         // (3) H1 reads done
    #pragma unroll
    for (int m = 0; m < 2; m++) {
      const int rr = r2 + m * 16;
      #pragma unroll
      for (int et = 0; et < 8; et++) {
        uint2 sv;
        sv.x = pack2relu(acc[m][et][0], acc[m][et][1]);
        sv.y = pack2relu(acc[m][et][2], acc[m][et][3]);
        *(uint2*)(H2 + (et * 16 + l16) * LD2 + rr) = sv;
      }
    }
  }
  __syncthreads();                                           // (4)

  // hoisted epilogue loads (overlap with GEMM3/softmax/fts)
  float scv = 0.f;
  if (t < 128) scv = SCb[blk * 128 + t];
  float* outp = out + ((b << 7) + (t & 127)) * 128 + n;

  // ---- GEMM3 + logits: wave owns att-rows wid*16..+15; acc init = bbA ----
  {
    short8 a3[4];
    #pragma unroll
    for (int ks = 0; ks < 4; ks++)
      a3[ks] = *(const short8*)(Wa0f + (wid * 16 + l16) * 128 + ks * 32 + koff);
    const int rr = wid * 16 + quad * 4;
    const float4 bb = *(const float4*)(baf + rr);
    const float4 wv = *(const float4*)(wa1f + rr);
    floatx4 binit; binit[0] = bb.x; binit[1] = bb.y; binit[2] = bb.z; binit[3] = bb.w;
    floatx4 acc[8];
    #pragma unroll
    for (int et = 0; et < 8; et++) acc[et] = binit;
    #pragma unroll
    for (int et = 0; et < 8; et++) {
      const u16* br = H2 + (et * 16 + l16) * LD2 + koff;
      #pragma unroll
      for (int ks = 0; ks < 4; ks++) {
        short8 bf = *(const short8*)(br + ks * 32);
        acc[et] = MFMA16(a3[ks], bf, acc[et]);
      }
    }
    #pragma unroll
    for (int et = 0; et < 8; et++) {
      float p = wv.x * fmaxf(acc[et][0], 0.f) + wv.y * fmaxf(acc[et][1], 0.f)
              + wv.z * fmaxf(acc[et][2], 0.f) + wv.w * fmaxf(acc[et][3], 0.f);
      p += __shfl_xor(p, 16); p += __shfl_xor(p, 32);
      if (quad == 0) parts[wid][et * 16 + l16] = p;
    }
  }
  __syncthreads();                                           // (5)

  // ---- softmax over 127 edges (wave 0) ----
  if (wid == 0) {
    float a0 = parts[0][lane] + parts[1][lane] + parts[2][lane] + parts[3][lane] + ba1v;
    float a1 = (lane == 63) ? -1e30f
             : (parts[0][lane + 64] + parts[1][lane + 64] + parts[2][lane + 64] + parts[3][lane + 64] + ba1v);
    float mx = fmaxf(a0, a1);
    #pragma unroll
    for (int off = 32; off >= 1; off >>= 1) mx = fmaxf(mx, __shfl_xor(mx, off));
    float e0 = expf(a0 - mx), e1 = expf(a1 - mx);
    float sm = e0 + e1;
    #pragma unroll
    for (int off = 32; off >= 1; off >>= 1) sm += __shfl_xor(sm, off);
    float inv = 1.f / sm;
    attws[lane] = e0 * inv;
    attws[lane + 64] = e1 * inv;   // attw[127] = 0
  }
  __syncthreads();                                           // (6)

  // ---- fts[c] = sum_e attw[e]*H2[e][c] ----
  {
    const int chg = t & 15, eg = t >> 4;   // 8 ch x 8 edges per thread
    float fa[8];
    #pragma unroll
    for (int k = 0; k < 8; k++) fa[k] = 0.f;
    #pragma unroll
    for (int i = 0; i < 8; i++) {
      const int e = eg * 8 + i;
      const float w = attws[e];
      uint4 v = *(const uint4*)(H2 + e * LD2 + chg * 8);
      unsigned u;
      u = v.x; fa[0] += w * bits2f(u << 16); fa[1] += w * bits2f(u & 0xffff0000u);
      u = v.y; fa[2] += w * bits2f(u << 16); fa[3] += w * bits2f(u & 0xffff0000u);
      u = v.z; fa[4] += w * bits2f(u << 16); fa[5] += w * bits2f(u & 0xffff0000u);
      u = v.w; fa[6] += w * bits2f(u << 16); fa[7] += w * bits2f(u & 0xffff0000u);
    }
    #pragma unroll
    for (int k = 0; k < 8; k++) { fa[k] += __shfl_xor(fa[k], 16); fa[k] += __shfl_xor(fa[k], 32); }
    if (lane < 16) {
      #pragma unroll
      for (int k = 0; k < 8; k++) parts[wid][chg * 8 + k] = fa[k];
    }
  }
  __syncthreads();                                           // (7)

  if (t < 128) {
    float fts = parts[0][t] + parts[1][t] + parts[2][t] + parts[3][t];
    *outp = fmaxf(scv + fts, 0.f);
  }
}

// ------------------------------------------------------------------
extern "C" void kernel_launch(void* const* d_in, const int* in_sizes, int n_in,
                              void* d_out, int out_size, void* d_ws, size_t ws_size,
                              hipStream_t stream)
{
  (void)d_ws; (void)ws_size; (void)in_sizes; (void)n_in; (void)out_size;
  const float* feat = (const float*)d_in[0];
  const float *w0 = (const float*)d_in[1],  *g0 = (const float*)d_in[2],  *b0 = (const float*)d_in[3],  *m0 = (const float*)d_in[4],  *v0 = (const float*)d_in[5];
  const float *w1 = (const float*)d_in[6],  *g1 = (const float*)d_in[7],  *b1 = (const float*)d_in[8],  *m1 = (const float*)d_in[9],  *v1 = (const float*)d_in[10];
  const float *w2 = (const float*)d_in[11], *g2 = (const float*)d_in[12], *b2 = (const float*)d_in[13], *m2 = (const float*)d_in[14], *v2 = (const float*)d_in[15];
  const float *wa0= (const float*)d_in[16], *ga = (const float*)d_in[17], *ba = (const float*)d_in[18], *ma = (const float*)d_in[19], *va = (const float*)d_in[20];
  const float *wa1= (const float*)d_in[21], *ba1= (const float*)d_in[22];
  const float *wsc= (const float*)d_in[23], *gsc= (const float*)d_in[24], *bsc= (const float*)d_in[25], *msc= (const float*)d_in[26], *vsc= (const float*)d_in[27];

  k_pre<<<dim3(513), dim3(256), 0, stream>>>(
      feat, w0, g0, b0, m0, v0, w1, g1, b1, m1, v1, w2, g2, b2, m2, v2,
      wa0, ga, ba, ma, va, wa1, ba1, wsc, gsc, bsc, msc, vsc);
  k_main<<<dim3(4096), dim3(256), 0, stream>>>((float*)d_out);
}

// Round 9
// 166.481 us; speedup vs baseline: 1.9412x; 1.0005x over previous
//
#include <hip/hip_runtime.h>

typedef unsigned short u16;
typedef short short8 __attribute__((ext_vector_type(8)));
typedef float floatx4 __attribute__((ext_vector_type(4)));
typedef __bf16 bf16x2 __attribute__((ext_vector_type(2)));

#define MFMA16(a, b, c) __builtin_amdgcn_mfma_f32_16x16x32_bf16((a), (b), (c), 0, 0, 0)

// ---- g_ws byte offsets (256-aligned) ----
#define W1F_OFF   0u         // bf16[4096]
#define B1F_OFF   8192u      // f32[64]
#define W2F_OFF   8448u      // bf16[8192]
#define B2F_OFF   24832u     // f32[128]
#define WA0F_OFF  25344u     // bf16[8192]
#define BAF_OFF   41728u     // f32[64]
#define WA1F_OFF  41984u     // f32[64]
#define BA1F_OFF  42240u     // f32[1]
#define P_OFF     42496u     // f32[32*128*64]
#define Q_OFF     1091072u   // f32[32*128*64]
#define SC_OFF    2139648u   // f32[32*128*128]
#define WS_TOTAL  4236800u

__device__ __align__(256) char g_ws[WS_TOTAL];

#define LD0 72    // u16 row stride (64-ch) — 16B-aligned rows
#define LD2 136   // u16 row stride (128-ch) — 16B-aligned rows

__device__ __forceinline__ float bits2f(unsigned u) {
  union { unsigned i; float f; } v; v.i = u; return v.f;
}
__device__ __forceinline__ unsigned f2bits(float f) {
  union { float f; unsigned i; } v; v.f = f; return v.i;
}
__device__ __forceinline__ u16 f2bf(float f) {
  return (u16)((f2bits(f) + 0x8000u) >> 16);
}
// two fp32 -> relu -> packed bf16 pair. gfx950: 2 fmax + 1 v_cvt_pk_bf16_f32.
__device__ __forceinline__ unsigned pack2relu(float a, float b) {
#if __has_builtin(__builtin_amdgcn_cvt_pk_bf16_f32)
  union { bf16x2 h; unsigned u; } cv;
  cv.h = __builtin_amdgcn_cvt_pk_bf16_f32(fmaxf(a, 0.f), fmaxf(b, 0.f));
  return cv.u;
#else
  unsigned lo = (f2bits(fmaxf(a, 0.f)) + 0x8000u) >> 16;
  unsigned hi = (f2bits(fmaxf(b, 0.f)) + 0x8000u) & 0xffff0000u;
  return lo | hi;
#endif
}

// ------------------------------------------------------------------
// k_pre: 513 blocks x 256.  (unchanged — ~13 us, not the pole)
//   blocks   0..255: P/Q for (b = sub>>3, n0 = (sub&7)*16)
//   blocks 256..511: SC  for same (b, n0)
//   block  512:      fold W1/W2/Wa0 (bf16) + biases
// ------------------------------------------------------------------
__global__ __launch_bounds__(256) void k_pre(
    const float* __restrict__ feat, const float* __restrict__ w0,
    const float* __restrict__ g0, const float* __restrict__ b0, const float* __restrict__ m0, const float* __restrict__ v0,
    const float* __restrict__ w1, const float* __restrict__ g1, const float* __restrict__ b1, const float* __restrict__ m1, const float* __restrict__ v1,
    const float* __restrict__ w2, const float* __restrict__ g2, const float* __restrict__ b2, const float* __restrict__ m2, const float* __restrict__ v2,
    const float* __restrict__ wa0, const float* __restrict__ ga, const float* __restrict__ ba, const float* __restrict__ ma, const float* __restrict__ va,
    const float* __restrict__ wa1, const float* __restrict__ ba1,
    const float* __restrict__ wsc, const float* __restrict__ gsc, const float* __restrict__ bsc, const float* __restrict__ msc, const float* __restrict__ vsc)
{
  __shared__ float smem[9600];
  const int t = threadIdx.x;
  char* ws = g_ws;
  const int blk = blockIdx.x;

  if (blk == 512) {
    float* fs1 = smem; float* fs2 = smem + 64; float* fsa = smem + 192;
    if (t < 64) {
      float s;
      s = g1[t] * rsqrtf(v1[t] + 1e-5f); fs1[t] = s; ((float*)(ws + B1F_OFF))[t] = b1[t] - m1[t] * s;
      s = ga[t] * rsqrtf(va[t] + 1e-5f); fsa[t] = s; ((float*)(ws + BAF_OFF))[t] = ba[t] - ma[t] * s;
      ((float*)(ws + WA1F_OFF))[t] = wa1[t];
    }
    if (t < 128) { float s = g2[t] * rsqrtf(v2[t] + 1e-5f); fs2[t] = s; ((float*)(ws + B2F_OFF))[t] = b2[t] - m2[t] * s; }
    if (t == 0) ((float*)(ws + BA1F_OFF))[0] = ba1[0];
    __syncthreads();
    u16* W1f = (u16*)(ws + W1F_OFF);
    u16* W2f = (u16*)(ws + W2F_OFF);
    u16* Wa0f = (u16*)(ws + WA0F_OFF);
    for (int i = t; i < 4096; i += 256) W1f[i]  = f2bf(fs1[i >> 6] * w1[i]);
    for (int i = t; i < 8192; i += 256) W2f[i]  = f2bf(fs2[i >> 6] * w2[i]);
    for (int i = t; i < 8192; i += 256) Wa0f[i] = f2bf(fsa[i >> 7] * wa0[i]);
    return;
  }

  const int sub = blk & 255;
  const int b = sub >> 3, n0 = (sub & 7) << 4;
  float* Xs  = smem;          // [64][20]
  float* Wsm = smem + 1280;

  {
    const int c = t >> 2, j = (t & 3) << 2;
    *(float4*)(Xs + c * 20 + j) = *(const float4*)(feat + b * 8192 + c * 128 + n0 + j);
  }

  if (blk < 256) {
    #pragma unroll
    for (int r = 0; r < 8; r++) {
      const int i = (r * 256 + t) * 4;
      float4 v = *(const float4*)(w0 + i);
      const int o = i >> 7, c = i & 127;
      float* d = Wsm + o * 129 + c;
      d[0] = v.x; d[1] = v.y; d[2] = v.z; d[3] = v.w;
    }
    __syncthreads();
    const int o = t & 63, nb = (t >> 6) << 2;
    const float s  = g0[o] * rsqrtf(v0[o] + 1e-5f);
    const float tt = b0[o] - m0[o] * s;
    const float* wr = Wsm + o * 129;
    float dA0=0.f,dA1=0.f,dA2=0.f,dA3=0.f,dB0=0.f,dB1=0.f,dB2=0.f,dB3=0.f;
    #pragma unroll
    for (int c = 0; c < 64; c++) {
      const float a = wr[c], e = wr[64 + c];
      const float4 x = *(const float4*)(Xs + c * 20 + nb);
      dA0 += a * x.x; dA1 += a * x.y; dA2 += a * x.z; dA3 += a * x.w;
      dB0 += e * x.x; dB1 += e * x.y; dB2 += e * x.z; dB3 += e * x.w;
    }
    float* Pp = (float*)(ws + P_OFF) + (b * 128 + n0 + nb) * 64 + o;
    float* Qp = (float*)(ws + Q_OFF) + (b * 128 + n0 + nb) * 64 + o;
    Pp[0]   = s * dB0; Pp[64]  = s * dB1; Pp[128] = s * dB2; Pp[192] = s * dB3;
    Qp[0]   = s * (dA0 - dB0) + tt; Qp[64]  = s * (dA1 - dB1) + tt;
    Qp[128] = s * (dA2 - dB2) + tt; Qp[192] = s * (dA3 - dB3) + tt;
  } else {
    #pragma unroll
    for (int r = 0; r < 8; r++) {
      const int i = (r * 256 + t) * 4;
      float4 v = *(const float4*)(wsc + i);
      const int o = i >> 6, c = i & 63;
      float* d = Wsm + o * 65 + c;
      d[0] = v.x; d[1] = v.y; d[2] = v.z; d[3] = v.w;
    }
    __syncthreads();
    const int o = t & 127, h = (t >> 7) << 3;
    const float s  = gsc[o] * rsqrtf(vsc[o] + 1e-5f);
    const float tt = bsc[o] - msc[o] * s;
    const float* wr = Wsm + o * 65;
    float d0=0.f,d1=0.f,d2=0.f,d3=0.f,d4=0.f,d5=0.f,d6=0.f,d7=0.f;
    #pragma unroll
    for (int c = 0; c < 64; c++) {
      const float a = wr[c];
      const float4 x0 = *(const float4*)(Xs + c * 20 + h);
      const float4 x1 = *(const float4*)(Xs + c * 20 + h + 4);
      d0 += a * x0.x; d1 += a * x0.y; d2 += a * x0.z; d3 += a * x0.w;
      d4 += a * x1.x; d5 += a * x1.y; d6 += a * x1.z; d7 += a * x1.w;
    }
    float* SCp = (float*)(ws + SC_OFF) + (b * 128 + n0 + h) * 128 + o;
    SCp[0]   = s * d0 + tt; SCp[128] = s * d1 + tt; SCp[256] = s * d2 + tt; SCp[384] = s * d3 + tt;
    SCp[512] = s * d4 + tt; SCp[640] = s * d5 + tt; SCp[768] = s * d6 + tt; SCp[896] = s * d7 + tt;
  }
}

// ------------------------------------------------------------------
// k_main: fused edge chain per (b,n). 4096 blocks x 256 thr (4 waves).
// R9: all relu+bf16-pack epilogues via v_cvt_pk_bf16_f32 (3 VALU/pair
// vs 7). Structure identical to R8.
// ------------------------------------------------------------------
__global__ __launch_bounds__(256, 4) void k_main(float* __restrict__ out)
{
  __shared__ alignas(16) u16 buf[18432];     // H0@0, H1@9216(u16); H2 overlays @0 (stride 136)
  __shared__ float parts[4][128];
  __shared__ float attws[128];

  const int blk = blockIdx.x, b = blk >> 7, n = blk & 127, t = threadIdx.x;
  const char* ws = g_ws;
  const float* Pb  = (const float*)(ws + P_OFF);
  const float* Qb  = (const float*)(ws + Q_OFF);
  const float* SCb = (const float*)(ws + SC_OFF);
  const u16*   W1f = (const u16*)(ws + W1F_OFF);
  const float* b1f = (const float*)(ws + B1F_OFF);
  const u16*   W2f = (const u16*)(ws + W2F_OFF);
  const float* b2f = (const float*)(ws + B2F_OFF);
  const u16*   Wa0f= (const u16*)(ws + WA0F_OFF);
  const float* baf = (const float*)(ws + BAF_OFF);
  const float* wa1f= (const float*)(ws + WA1F_OFF);
  const float  ba1v= *(const float*)(ws + BA1F_OFF);

  u16* H0 = buf;
  u16* H1 = buf + 9216;
  u16* H2 = buf;            // after barrier (3)

  const int lane = t & 63, wid = t >> 6, quad = lane >> 4, l16 = lane & 15;
  const int koff = quad * 8;

  // hoisted A-fragments (no LDS dependence)
  const short8 a1w0 = *(const short8*)(W1f + (wid * 16 + l16) * 64 + koff);
  const short8 a1w1 = *(const short8*)(W1f + (wid * 16 + l16) * 64 + 32 + koff);
  const short8 a2w00 = *(const short8*)(W2f + (wid * 32 + l16) * 64 + koff);
  const short8 a2w01 = *(const short8*)(W2f + (wid * 32 + l16) * 64 + 32 + koff);
  const short8 a2w10 = *(const short8*)(W2f + (wid * 32 + 16 + l16) * 64 + koff);
  const short8 a2w11 = *(const short8*)(W2f + (wid * 32 + 16 + l16) * 64 + 32 + koff);

  // ---- L0: H0[edge][ch] = relu(Q[b,n] + P[b,j]); edge 127 dummy ----
  {
    const int k = t >> 1, half = t & 1;
    const int j = (k < 127) ? ((k < n) ? k : (k + 1)) : n;
    const float4* pr = (const float4*)(Pb + ((b << 7) + j) * 64 + half * 32);
    const float4* qr = (const float4*)(Qb + blk * 64 + half * 32);
    u16* dst = H0 + k * LD0 + half * 32;
    #pragma unroll
    for (int i = 0; i < 8; i++) {
      float4 p = pr[i], q = qr[i];
      uint2 sv;
      sv.x = pack2relu(q.x + p.x, q.y + p.y);
      sv.y = pack2relu(q.z + p.z, q.w + p.w);
      *(uint2*)(dst + i * 4) = sv;
    }
  }
  __syncthreads();                                           // (1)

  // ---- GEMM1: wave owns rows wid*16..+15 of H1; acc init = bias ----
  {
    const int rr = wid * 16 + quad * 4;
    const float4 bb = *(const float4*)(b1f + rr);
    floatx4 binit; binit[0] = bb.x; binit[1] = bb.y; binit[2] = bb.z; binit[3] = bb.w;
    floatx4 acc[8];
    #pragma unroll
    for (int et = 0; et < 8; et++) acc[et] = binit;
    #pragma unroll
    for (int et = 0; et < 8; et++) {
      const u16* br = H0 + (et * 16 + l16) * LD0 + koff;
      short8 bf0 = *(const short8*)(br);
      short8 bf1 = *(const short8*)(br + 32);
      acc[et] = MFMA16(a1w0, bf0, acc[et]);
      acc[et] = MFMA16(a1w1, bf1, acc[et]);
    }
    #pragma unroll
    for (int et = 0; et < 8; et++) {
      uint2 sv;
      sv.x = pack2relu(acc[et][0], acc[et][1]);
      sv.y = pack2relu(acc[et][2], acc[et][3]);
      *(uint2*)(H1 + (et * 16 + l16) * LD0 + rr) = sv;
    }
  }
  __syncthreads();                                           // (2)

  // ---- GEMM2: wave owns rows wid*32..+31 of H2; register-staged ----
  {
    const int r2 = wid * 32 + quad * 4;
    const float4 bba = *(const float4*)(b2f + r2);
    const float4 bbb = *(const float4*)(b2f + r2 + 16);
    floatx4 ia; ia[0] = bba.x; ia[1] = bba.y; ia[2] = bba.z; ia[3] = bba.w;
    floatx4 ib; ib[0] = bbb.x; ib[1] = bbb.y; ib[2] = bbb.z; ib[3] = bbb.w;
    floatx4 acc[2][8];
    #pragma unroll
    for (int et = 0; et < 8; et++) { acc[0][et] = ia; acc[1][et] = ib; }
    #pragma unroll
    for (int et = 0; et < 8; et++) {
      const u16* br = H1 + (et * 16 + l16) * LD0 + koff;
      short8 bf0 = *(const short8*)(br);
      short8 bf1 = *(const short8*)(br + 32);
      acc[0][et] = MFMA16(a2w00, bf0, acc[0][et]);
      acc[0][et] = MFMA16(a2w01, bf1, acc[0][et]);
      acc[1][et] = MFMA16(a2w10, bf0, acc[1][et]);
      acc[1][et] = MFMA16(a2w11, bf1, acc[1][et]);
    }
    __syncthreads();                                         // (3) H1 reads done
    #pragma unroll
    for (int m = 0; m < 2; m++) {
      const int rr = r2 + m * 16;
      #pragma unroll
      for (int et = 0; et < 8; et++) {
        uint2 sv;
        sv.x = pack2relu(acc[m][et][0], acc[m][et][1]);
        sv.y = pack2relu(acc[m][et][2], acc[m][et][3]);
        *(uint2*)(H2 + (et * 16 + l16) * LD2 + rr) = sv;
      }
    }
  }
  __syncthreads();                                           // (4)

  // hoisted epilogue loads (overlap with GEMM3/softmax/fts)
  float scv = 0.f;
  if (t < 128) scv = SCb[blk * 128 + t];
  float* outp = out + ((b << 7) + (t & 127)) * 128 + n;

  // ---- GEMM3 + logits: wave owns att-rows wid*16..+15; acc init = bbA ----
  {
    short8 a3[4];
    #pragma unroll
    for (int ks = 0; ks < 4; ks++)
      a3[ks] = *(const short8*)(Wa0f + (wid * 16 + l16) * 128 + ks * 32 + koff);
    const int rr = wid * 16 + quad * 4;
    const float4 bb = *(const float4*)(baf + rr);
    const float4 wv = *(const float4*)(wa1f + rr);
    floatx4 binit; binit[0] = bb.x; binit[1] = bb.y; binit[2] = bb.z; binit[3] = bb.w;
    floatx4 acc[8];
    #pragma unroll
    for (int et = 0; et < 8; et++) acc[et] = binit;
    #pragma unroll
    for (int et = 0; et < 8; et++) {
      const u16* br = H2 + (et * 16 + l16) * LD2 + koff;
      #pragma unroll
      for (int ks = 0; ks < 4; ks++) {
        short8 bf = *(const short8*)(br + ks * 32);
        acc[et] = MFMA16(a3[ks], bf, acc[et]);
      }
    }
    #pragma unroll
    for (int et = 0; et < 8; et++) {
      float p = wv.x * fmaxf(acc[et][0], 0.f) + wv.y * fmaxf(acc[et][1], 0.f)
              + wv.z * fmaxf(acc[et][2], 0.f) + wv.w * fmaxf(acc[et][3], 0.f);
      p += __shfl_xor(p, 16); p += __shfl_xor(p, 32);
      if (quad == 0) parts[wid][et * 16 + l16] = p;
    }
  }
  __syncthreads();                                           // (5)

  // ---- softmax over 127 edges (wave 0) ----
  if (wid == 0) {
    float a0 = parts[0][lane] + parts[1][lane] + parts[2][lane] + parts[3][lane] + ba1v;
    float a1 = (lane == 63) ? -1e30f
             : (parts[0][lane + 64] + parts[1][lane + 64] + parts[2][lane + 64] + parts[3][lane + 64] + ba1v);
    float mx = fmaxf(a0, a1);
    #pragma unroll
    for (int off = 32; off >= 1; off >>= 1) mx = fmaxf(mx, __shfl_xor(mx, off));
    float e0 = expf(a0 - mx), e1 = expf(a1 - mx);
    float sm = e0 + e1;
    #pragma unroll
    for (int off = 32; off >= 1; off >>= 1) sm += __shfl_xor(sm, off);
    float inv = 1.f / sm;
    attws[lane] = e0 * inv;
    attws[lane + 64] = e1 * inv;   // attw[127] = 0
  }
  __syncthreads();                                           // (6)

  // ---- fts[c] = sum_e attw[e]*H2[e][c] ----
  {
    const int chg = t & 15, eg = t >> 4;   // 8 ch x 8 edges per thread
    float fa[8];
    #pragma unroll
    for (int k = 0; k < 8; k++) fa[k] = 0.f;
    #pragma unroll
    for (int i = 0; i < 8; i++) {
      const int e = eg * 8 + i;
      const float w = attws[e];
      uint4 v = *(const uint4*)(H2 + e * LD2 + chg * 8);
      unsigned u;
      u = v.x; fa[0] += w * bits2f(u << 16); fa[1] += w * bits2f(u & 0xffff0000u);
      u = v.y; fa[2] += w * bits2f(u << 16); fa[3] += w * bits2f(u & 0xffff0000u);
      u = v.z; fa[4] += w * bits2f(u << 16); fa[5] += w * bits2f(u & 0xffff0000u);
      u = v.w; fa[6] += w * bits2f(u << 16); fa[7] += w * bits2f(u & 0xffff0000u);
    }
    #pragma unroll
    for (int k = 0; k < 8; k++) { fa[k] += __shfl_xor(fa[k], 16); fa[k] += __shfl_xor(fa[k], 32); }
    if (lane < 16) {
      #pragma unroll
      for (int k = 0; k < 8; k++) parts[wid][chg * 8 + k] = fa[k];
    }
  }
  __syncthreads();                                           // (7)

  if (t < 128) {
    float fts = parts[0][t] + parts[1][t] + parts[2][t] + parts[3][t];
    *outp = fmaxf(scv + fts, 0.f);
  }
}

// ------------------------------------------------------------------
extern "C" void kernel_launch(void* const* d_in, const int* in_sizes, int n_in,
                              void* d_out, int out_size, void* d_ws, size_t ws_size,
                              hipStream_t stream)
{
  (void)d_ws; (void)ws_size; (void)in_sizes; (void)n_in; (void)out_size;
  const float* feat = (const float*)d_in[0];
  const float *w0 = (const float*)d_in[1],  *g0 = (const float*)d_in[2],  *b0 = (const float*)d_in[3],  *m0 = (const float*)d_in[4],  *v0 = (const float*)d_in[5];
  const float *w1 = (const float*)d_in[6],  *g1 = (const float*)d_in[7],  *b1 = (const float*)d_in[8],  *m1 = (const float*)d_in[9],  *v1 = (const float*)d_in[10];
  const float *w2 = (const float*)d_in[11], *g2 = (const float*)d_in[12], *b2 = (const float*)d_in[13], *m2 = (const float*)d_in[14], *v2 = (const float*)d_in[15];
  const float *wa0= (const float*)d_in[16], *ga = (const float*)d_in[17], *ba = (const float*)d_in[18], *ma = (const float*)d_in[19], *va = (const float*)d_in[20];
  const float *wa1= (const float*)d_in[21], *ba1= (const float*)d_in[22];
  const float *wsc= (const float*)d_in[23], *gsc= (const float*)d_in[24], *bsc= (const float*)d_in[25], *msc= (const float*)d_in[26], *vsc= (const float*)d_in[27];

  k_pre<<<dim3(513), dim3(256), 0, stream>>>(
      feat, w0, g0, b0, m0, v0, w1, g1, b1, m1, v1, w2, g2, b2, m2, v2,
      wa0, ga, ba, ma, va, wa1, ba1, wsc, gsc, bsc, msc, vsc);
  k_main<<<dim3(4096), dim3(256), 0, stream>>>((float*)d_out);
}